// Round 4
// baseline (192.144 us; speedup 1.0000x reference)
//
#include <hip/hip_runtime.h>
#include <hip/hip_bf16.h>

#define NB 128
#define NQ 900
#define NT 256
#define NG 20
#define NR 15                 // pred rows per lane in match: 64*15 >= 900
#define FOCAL_BLOCKS 1800
#define MATCH_BLOCKS 128
#define TOTAL_BLOCKS (FOCAL_BLOCKS + MATCH_BLOCKS)
#define FWAVES (FOCAL_BLOCKS * 4)   // 7200 focal waves; 16 rows each = 115200 rows

// ws layout (floats): [0,7200) focal per-wave partials
//                     [7200,7328) bbox per-batch, [7328,7456) giou, [7456,7584) delta
#define WS_BB 7200
#define WS_GI 7328
#define WS_DL 7456

__device__ __forceinline__ float clamp01(float v) {
    return fminf(fmaxf(v, 0.0f), 1.0f);
}

// focal(x, target=0) WITHOUT the 0.75 alpha (folded into finalize).
__device__ __forceinline__ float focal_neg_term(float x) {
    float ax  = fabsf(x);
    float em  = __expf(-ax);
    float a1  = 1.0f + em;
    float ce  = fmaxf(x, 0.0f) + __logf(a1);
    float inv = __builtin_amdgcn_rcpf(a1);
    float p   = (x >= 0.0f) ? inv : em * inv;
    return ce * p * p;
}

// focal(x,1) - focal(x,0), full alpha factors included.
__device__ __forceinline__ float focal_delta_term(float x) {
    float ax     = fabsf(x);
    float em     = __expf(-ax);
    float a1     = 1.0f + em;
    float lg     = __logf(a1);
    float ce0    = fmaxf(x, 0.0f) + lg;
    float ce1    = ce0 - x;
    float inv    = __builtin_amdgcn_rcpf(a1);
    float em_inv = em * inv;
    float p      = (x >= 0.0f) ? inv : em_inv;   // sigmoid(x)
    float omp    = (x >= 0.0f) ? em_inv : inv;   // 1 - p
    return 0.25f * ce1 * omp * omp - 0.75f * ce0 * p * p;
}

__device__ __forceinline__ float focal_row_sum4(float4 v) {
    return focal_neg_term(v.x) + focal_neg_term(v.y) +
           focal_neg_term(v.z) + focal_neg_term(v.w);
}

// ---------------------------------------------------------------------------
// Fused kernel. Blocks [0,MATCH_BLOCKS): per-batch greedy match + bbox L1 +
// GIoU + span focal-correction, single active wave, no LDS, no atomics.
// Blocks [MATCH_BLOCKS, TOTAL): focal(target=0) baseline, 2 iterations of
// 8 independent row loads per wave (2 KB/lane-group in flight).
// ---------------------------------------------------------------------------
__global__ __launch_bounds__(256) void main_kernel(
    const float4* __restrict__ logits,      // [B*Q*T/4]
    const float4* __restrict__ pred_boxes,  // [B*Q] cxcywh
    const float4* __restrict__ tgt_boxes,   // [B*G] cxcywh
    const int2*   __restrict__ tokens,      // [B*G] (start, end)
    float*        __restrict__ ws)          // partials, see layout above
{
    if (blockIdx.x >= MATCH_BLOCKS) {
        // ----------------- focal(target=0) baseline path -----------------
        const int lane = threadIdx.x & 63;
        const int gw   = ((blockIdx.x - MATCH_BLOCKS) * 256 + threadIdx.x) >> 6;

        float sum = 0.0f;
        #pragma unroll
        for (int i = 0; i < 2; ++i) {
            int row0 = (gw + i * FWAVES) * 8;
            const float4* base = logits + (size_t)row0 * (NT / 4) + lane;
            float4 v0 = base[0 * (NT / 4)];
            float4 v1 = base[1 * (NT / 4)];
            float4 v2 = base[2 * (NT / 4)];
            float4 v3 = base[3 * (NT / 4)];
            float4 v4 = base[4 * (NT / 4)];
            float4 v5 = base[5 * (NT / 4)];
            float4 v6 = base[6 * (NT / 4)];
            float4 v7 = base[7 * (NT / 4)];
            sum += focal_row_sum4(v0) + focal_row_sum4(v1) +
                   focal_row_sum4(v2) + focal_row_sum4(v3) +
                   focal_row_sum4(v4) + focal_row_sum4(v5) +
                   focal_row_sum4(v6) + focal_row_sum4(v7);
        }
        #pragma unroll
        for (int off = 32; off > 0; off >>= 1) sum += __shfl_down(sum, off);
        if (lane == 0) ws[gw] = sum;    // unconditional per-wave partial
        return;
    }

    // ----------------- match path: one wave per batch -----------------
    if (threadIdx.x >= 64) return;        // waves 1..3 idle; no syncthreads used
    const int b    = blockIdx.x;
    const int lane = threadIdx.x;

    // Each lane owns pred rows q = lane + 64*r in registers.
    float px1[NR], py1[NR], px2[NR], py2[NR], pa[NR];
    int avail = 0;
    #pragma unroll
    for (int r = 0; r < NR; ++r) {
        int q = lane + 64 * r;
        if (q < NQ) {
            float4 pb = pred_boxes[b * NQ + q];
            px1[r] = pb.x - 0.5f * pb.z; py1[r] = pb.y - 0.5f * pb.w;
            px2[r] = pb.x + 0.5f * pb.z; py2[r] = pb.y + 0.5f * pb.w;
            pa[r]  = (px2[r] - px1[r]) * (py2[r] - py1[r]);
            avail |= (1 << r);
        } else {
            px1[r] = 0.0f; py1[r] = 0.0f; px2[r] = 0.0f; py2[r] = 0.0f;
            pa[r] = 0.0f;
        }
    }

    int my_q = 0;   // matched q for g == lane (lanes 0..19)
    for (int g = 0; g < NG; ++g) {
        float4 tb = tgt_boxes[b * NG + g];          // broadcast load (L1)
        float gx1 = tb.x - 0.5f * tb.z, gy1 = tb.y - 0.5f * tb.w;
        float gx2 = tb.x + 0.5f * tb.z, gy2 = tb.y + 0.5f * tb.w;
        float ga  = (gx2 - gx1) * (gy2 - gy1);
        float bv = -2.0f;
        int   bi = 0x7fffffff;
        #pragma unroll
        for (int r = 0; r < NR; ++r) {
            float ix1 = fmaxf(px1[r], gx1), iy1 = fmaxf(py1[r], gy1);
            float ix2 = fminf(px2[r], gx2), iy2 = fminf(py2[r], gy2);
            float iw = fmaxf(ix2 - ix1, 0.0f), ih = fmaxf(iy2 - iy1, 0.0f);
            float inter = iw * ih;
            float v = inter / (pa[r] + ga - inter);   // exact div, matches ref
            bool ok = (avail >> r) & 1;
            v = ok ? v : -1.0f;                       // also kills q>=900 NaNs
            int q = lane + 64 * r;
            if (v > bv) { bv = v; bi = q; }           // strict >: first max per lane
        }
        #pragma unroll
        for (int off = 1; off < 64; off <<= 1) {
            float ov = __shfl_xor(bv, off);
            int   oi = __shfl_xor(bi, off);
            if (ov > bv || (ov == bv && oi < bi)) { bv = ov; bi = oi; }
        }
        if (lane == g) my_q = bi;
        if ((bi & 63) == lane) avail &= ~(1 << (bi >> 6));  // remove matched row
    }

    // Epilogue: bbox L1 + GIoU + span focal-correction for g = lane < 20.
    float lb = 0.0f, lgi = 0.0f, dl = 0.0f;
    if (lane < NG) {
        int g = lane, q = my_q;
        float4 pb = pred_boxes[b * NQ + q];
        float4 tb = tgt_boxes[b * NG + g];
        lb = fabsf(pb.x - tb.x) + fabsf(pb.y - tb.y) +
             fabsf(pb.z - tb.z) + fabsf(pb.w - tb.w);

        float mx1 = pb.x - 0.5f * pb.z, my1 = pb.y - 0.5f * pb.w;
        float mx2 = pb.x + 0.5f * pb.z, my2 = pb.y + 0.5f * pb.w;
        mx2 = fmaxf(mx2, mx1 + 1e-6f);  my2 = fmaxf(my2, my1 + 1e-6f);
        mx1 = clamp01(mx1); my1 = clamp01(my1);
        mx2 = clamp01(mx2); my2 = clamp01(my2);

        float gx1 = tb.x - 0.5f * tb.z, gy1 = tb.y - 0.5f * tb.w;
        float gx2 = tb.x + 0.5f * tb.z, gy2 = tb.y + 0.5f * tb.w;
        gx2 = fmaxf(gx2, gx1 + 1e-6f);  gy2 = fmaxf(gy2, gy1 + 1e-6f);
        gx1 = clamp01(gx1); gy1 = clamp01(gy1);
        gx2 = clamp01(gx2); gy2 = clamp01(gy2);

        float a1 = (mx2 - mx1) * (my2 - my1);
        float a2 = (gx2 - gx1) * (gy2 - gy1);
        float ix1 = fmaxf(mx1, gx1), iy1 = fmaxf(my1, gy1);
        float ix2 = fminf(mx2, gx2), iy2 = fminf(my2, gy2);
        float iw = fmaxf(ix2 - ix1, 0.0f), ih = fmaxf(iy2 - iy1, 0.0f);
        float inter = iw * ih;
        float uni   = a1 + a2 - inter;
        float iou   = inter / uni;
        float cx1 = fminf(mx1, gx1), cy1 = fminf(my1, gy1);
        float cx2 = fmaxf(mx2, gx2), cy2 = fmaxf(my2, gy2);
        float ac  = fmaxf(cx2 - cx1, 0.0f) * fmaxf(cy2 - cy1, 0.0f);
        lgi = 1.0f - (iou - (ac - uni) / ac);

        // Span correction: sum focal(x,1)-focal(x,0) over the <=5 span tokens.
        int2 tk = tokens[b * NG + g];
        const float* rowp = (const float*)logits + (size_t)(b * NQ + q) * NT;
        for (int t = tk.x; t < tk.y; ++t) dl += focal_delta_term(rowp[t]);
    }
    #pragma unroll
    for (int off = 32; off > 0; off >>= 1) {
        lb  += __shfl_down(lb,  off);
        lgi += __shfl_down(lgi, off);
        dl  += __shfl_down(dl,  off);
    }
    if (lane == 0) {
        ws[WS_BB + b] = lb;
        ws[WS_GI + b] = lgi;
        ws[WS_DL + b] = dl;
    }
}

// ---------------------------------------------------------------------------
// Finalize: one block sums 7200 focal partials + 3x128 match partials,
// applies coefficients, writes the 4 outputs.
// ---------------------------------------------------------------------------
__global__ __launch_bounds__(256) void finalize_kernel(
    const float* __restrict__ ws, float* __restrict__ out)
{
    const int tid  = threadIdx.x;
    const int lane = tid & 63;
    const int wav  = tid >> 6;

    float s_neg = 0.0f;
    for (int i = tid; i < FWAVES; i += 256) s_neg += ws[i];
    float s_bb = 0.0f, s_gi = 0.0f, s_dl = 0.0f;
    if (tid < NB) {
        s_bb = ws[WS_BB + tid];
        s_gi = ws[WS_GI + tid];
        s_dl = ws[WS_DL + tid];
    }
    #pragma unroll
    for (int off = 32; off > 0; off >>= 1) {
        s_neg += __shfl_down(s_neg, off);
        s_bb  += __shfl_down(s_bb,  off);
        s_gi  += __shfl_down(s_gi,  off);
        s_dl  += __shfl_down(s_dl,  off);
    }
    __shared__ float red[4][4];
    if (lane == 0) {
        red[0][wav] = s_neg; red[1][wav] = s_bb;
        red[2][wav] = s_gi;  red[3][wav] = s_dl;
    }
    __syncthreads();
    if (tid == 0) {
        float neg = red[0][0] + red[0][1] + red[0][2] + red[0][3];
        float bb  = red[1][0] + red[1][1] + red[1][2] + red[1][3];
        float gi  = red[2][0] + red[2][1] + red[2][2] + red[2][3];
        float dlt = red[3][0] + red[3][1] + red[3][2] + red[3][3];
        const float num_boxes = (float)(NB * NG);          // 2560
        float lb = 5.0f * bb / num_boxes;
        float lg = 2.0f * gi / num_boxes;
        float cls_sum = 0.75f * neg + dlt;
        float lc = (cls_sum / (float)(NQ * NT)) / num_boxes;
        out[0] = lb;
        out[1] = lg;
        out[2] = lc;
        out[3] = lb + lg + lc;
    }
}

extern "C" void kernel_launch(void* const* d_in, const int* in_sizes, int n_in,
                              void* d_out, int out_size, void* d_ws, size_t ws_size,
                              hipStream_t stream) {
    const float4* pred_logits4 = (const float4*)d_in[0];  // (B,Q,T) f32
    const float4* pred_boxes4  = (const float4*)d_in[1];  // (B,Q,4) f32
    const float4* tgt_boxes4   = (const float4*)d_in[2];  // (B,G,4) f32
    const int2*   tokens2      = (const int2*)d_in[3];    // (B,G,2) i32

    float* ws = (float*)d_ws;   // 7584 floats, all slots written every call

    main_kernel<<<TOTAL_BLOCKS, 256, 0, stream>>>(pred_logits4, pred_boxes4,
                                                  tgt_boxes4, tokens2, ws);
    finalize_kernel<<<1, 256, 0, stream>>>(ws, (float*)d_out);
}